// Round 1
// baseline (18.638 us; speedup 1.0000x reference)
//
#include <hip/hip_runtime.h>

#define BB 4096
#define SS 256
#define NOPS 7

__global__ __launch_bounds__(256) void arth_kernel(
    const float* __restrict__ tv_in,
    const float* __restrict__ td_in,
    const float* __restrict__ op_in,
    const float* __restrict__ if_fin,
    const float* __restrict__ if_val,
    const int* __restrict__ start_pos_p,
    float* __restrict__ out_tv,
    float* __restrict__ out_td,
    float* __restrict__ out_op,
    float* __restrict__ out_iff,
    float* __restrict__ out_iv)
{
    __shared__ float s_op[SS * NOPS];
    __shared__ float s_tv[SS];
    __shared__ float s_td[SS];
    __shared__ unsigned char s_amax[SS];
    __shared__ unsigned long long sm_op[4];
    __shared__ unsigned long long sm_num[4];

    const int b = blockIdx.x;
    const int t = threadIdx.x;
    const size_t rbase = (size_t)b * SS;
    const size_t obase = (size_t)b * (SS * NOPS);
    const int start_pos = *start_pos_p;

    // Stage + copy trans_op row: 1792 floats = 448 float4 (coalesced).
    const float4* in4 = (const float4*)(op_in + obase);
    float4* o4 = (float4*)(out_op + obase);
    float4* s4 = (float4*)s_op;
    #pragma unroll
    for (int k = t; k < (SS * NOPS) / 4; k += 256) {
        float4 v = in4[k];
        o4[k] = v;
        s4[k] = v;
    }
    const float tvv = tv_in[rbase + t];
    const float tdv = td_in[rbase + t];
    s_tv[t] = tvv;
    s_td[t] = tdv;
    __syncthreads();

    // Per-position argmax over 7 ops (first-max-lowest-index, matches jnp.argmax).
    int am = 0;
    float best = s_op[t * NOPS];
    #pragma unroll
    for (int k = 1; k < NOPS; ++k) {
        float v = s_op[t * NOPS + k];
        if (v > best) { best = v; am = k; }
    }
    s_amax[t] = (unsigned char)am;

    const bool active = (t >= start_pos);
    const bool validtok = active && (tvv > 0.5f);
    const bool is_num = validtok && (am == 0);
    const bool is_op = validtok && (am != 0);

    unsigned long long mo = __ballot(is_op);
    unsigned long long mn = __ballot(is_num);
    if ((t & 63) == 0) {
        sm_op[t >> 6] = mo;
        sm_num[t >> 6] = mn;
    }
    __syncthreads();

    if (t == 0) {
        const bool finished = if_fin[b] > 0.5f;
        const float iv0 = if_val[b];
        float iff, ivout;
        if (finished) {
            // itv==0 everywhere: passthrough; iff=1; iv unchanged.
            iff = 1.0f;
            ivout = iv0;
        } else if (!(iv0 > 0.5f)) {
            // iv==0: no pushes, no ops, meet stays 0, hs stays 0 -> ifu=0.
            iff = 0.0f;
            ivout = 0.0f;
        } else {
            // Find first valid op token j.
            int j = -1;
            for (int ww = 0; ww < 4; ++ww) {
                unsigned long long m = sm_op[ww];
                if (m) { j = ww * 64 + __builtin_ctzll(m); break; }
            }
            // Top-two push indices strictly below j (or below S if no op).
            int i0 = -1, i1 = -1;
            for (int ww = 3; ww >= 0 && i1 < 0; --ww) {
                unsigned long long m = sm_num[ww];
                if (j >= 0) {
                    int jw = j - ww * 64;
                    if (jw <= 0) m = 0ull;
                    else if (jw < 64) m &= ((1ull << jw) - 1ull);
                }
                while (m && i1 < 0) {
                    int bit = 63 - __builtin_clzll(m);
                    if (i0 < 0) i0 = ww * 64 + bit;
                    else       i1 = ww * 64 + bit;
                    m &= ~(1ull << bit);
                }
            }
            if (j < 0) {
                // No op met: iv stays 1; iff = (exactly one push).
                ivout = 1.0f;
                iff = (i0 >= 0 && i1 < 0) ? 1.0f : 0.0f;
            } else if (i1 >= 0) {
                // fg==1: apply the op. h0 = top (most recent push), h1 = second.
                float h0 = s_td[i0];
                float h1 = s_td[i1];
                int op = s_amax[j];
                float res;
                switch (op) {
                    case 2: res = h1 + h0; break;
                    case 3: res = h1 - h0; break;
                    case 4: res = h1 * h0; break;
                    case 5: res = h1 / (h0 + 1e-7f); break;
                    case 6: res = powf(fmaxf(h1, 1e-7f), h0); break;
                    default: res = 0.0f; break;   // op index 1 -> zero
                }
                s_td[i0] = res;
                s_tv[i1] = 0.0f;
                s_tv[j] = 0.0f;
                ivout = 1.0f;
                iff = 0.0f;
            } else {
                // Op met but stack underflow: iv -> 0, nothing written.
                ivout = 0.0f;
                iff = 0.0f;
            }
        }
        out_iff[b] = iff;
        out_iv[b] = ivout;
    }
    __syncthreads();

    // Coalesced writeback of (possibly patched) tv/td rows.
    out_tv[rbase + t] = s_tv[t];
    out_td[rbase + t] = s_td[t];
}

extern "C" void kernel_launch(void* const* d_in, const int* in_sizes, int n_in,
                              void* d_out, int out_size, void* d_ws, size_t ws_size,
                              hipStream_t stream) {
    const float* tv_in = (const float*)d_in[0];   // trans_valid (B,S)
    const float* td_in = (const float*)d_in[1];   // trans_dense (B,S)
    const float* op_in = (const float*)d_in[2];   // trans_op (B,S,7)
    const float* if_fin = (const float*)d_in[3];  // if_finished (B,)
    const float* if_val = (const float*)d_in[4];  // if_valid (B,)
    const int* start_pos = (const int*)d_in[5];   // scalar

    float* out = (float*)d_out;
    float* out_tv = out;                                    // B*S
    float* out_td = out + (size_t)BB * SS;                  // B*S
    float* out_op = out + (size_t)2 * BB * SS;              // B*S*7
    float* out_iff = out + (size_t)9 * BB * SS;             // B
    float* out_iv = out + (size_t)9 * BB * SS + BB;         // B

    arth_kernel<<<BB, SS, 0, stream>>>(tv_in, td_in, op_in, if_fin, if_val,
                                       start_pos, out_tv, out_td, out_op,
                                       out_iff, out_iv);
}

// Round 2
// 17.873 us; speedup vs baseline: 1.0428x; 1.0428x over previous
//
#include <hip/hip_runtime.h>

#define BB 4096
#define SS 256
#define NOPS 7

__global__ __launch_bounds__(256) void arth_kernel(
    const float* __restrict__ tv_in,
    const float* __restrict__ td_in,
    const float* __restrict__ op_in,
    const float* __restrict__ if_fin,
    const float* __restrict__ if_val,
    const int* __restrict__ start_pos_p,
    float* __restrict__ out_tv,
    float* __restrict__ out_td,
    float* __restrict__ out_op,
    float* __restrict__ out_iff,
    float* __restrict__ out_iv)
{
    __shared__ float s_op[SS * NOPS];
    __shared__ float s_td[SS];
    __shared__ unsigned char s_amax[SS];
    __shared__ unsigned long long sm_op[4];
    __shared__ unsigned long long sm_num[4];

    const int b = blockIdx.x;
    const int t = threadIdx.x;
    const size_t rbase = (size_t)b * SS;
    const size_t obase = (size_t)b * (SS * NOPS);

    // Block-uniform scalar loads -> s_load, issued at the top so their
    // latency overlaps the op-row staging (previously these sat cold in the
    // thread-0 serial tail behind two barriers).
    const int start_pos = *start_pos_p;
    const float fin_f = if_fin[b];
    const float iv0 = if_val[b];

    // Stage + copy trans_op row: 1792 floats = 448 float4 (coalesced).
    const float4* in4 = (const float4*)(op_in + obase);
    float4* o4 = (float4*)(out_op + obase);
    float4* s4 = (float4*)s_op;
    #pragma unroll
    for (int k = t; k < (SS * NOPS) / 4; k += 256) {
        float4 v = in4[k];
        o4[k] = v;
        s4[k] = v;
    }
    const float tvv = tv_in[rbase + t];
    const float tdv = td_in[rbase + t];
    s_td[t] = tdv;
    __syncthreads();

    // Per-position argmax over 7 ops (first-max-lowest-index, matches jnp.argmax).
    int am = 0;
    float best = s_op[t * NOPS];
    #pragma unroll
    for (int k = 1; k < NOPS; ++k) {
        float v = s_op[t * NOPS + k];
        if (v > best) { best = v; am = k; }
    }
    s_amax[t] = (unsigned char)am;

    const bool validtok = (t >= start_pos) && (tvv > 0.5f);
    const bool is_num = validtok && (am == 0);
    const bool is_op = validtok && (am != 0);

    unsigned long long mo = __ballot(is_op);
    unsigned long long mn = __ballot(is_num);
    if ((t & 63) == 0) {
        sm_op[t >> 6] = mo;
        sm_num[t >> 6] = mn;
    }
    __syncthreads();

    // ALL threads redundantly scan the 8 mask words (wave-uniform control,
    // broadcast LDS reads) -> no third barrier, no LDS patch round-trip.
    unsigned long long w_op0 = sm_op[0], w_op1 = sm_op[1], w_op2 = sm_op[2], w_op3 = sm_op[3];
    unsigned long long w_nm[4] = { sm_num[0], sm_num[1], sm_num[2], sm_num[3] };

    // First valid op token j (or -1).
    int j = -1;
    if (w_op0)      j = __builtin_ctzll(w_op0);
    else if (w_op1) j = 64 + __builtin_ctzll(w_op1);
    else if (w_op2) j = 128 + __builtin_ctzll(w_op2);
    else if (w_op3) j = 192 + __builtin_ctzll(w_op3);

    // Top-two push indices strictly below j (or below S if no op).
    int i0 = -1, i1 = -1;
    #pragma unroll
    for (int ww = 3; ww >= 0; --ww) {
        if (i1 >= 0) continue;
        unsigned long long m = w_nm[ww];
        if (j >= 0) {
            int jw = j - ww * 64;
            if (jw <= 0) m = 0ull;
            else if (jw < 64) m &= ((1ull << jw) - 1ull);
        }
        while (m && i1 < 0) {
            int bit = 63 - __builtin_clzll(m);
            if (i0 < 0) i0 = ww * 64 + bit;
            else        i1 = ww * 64 + bit;
            m &= ~(1ull << bit);
        }
    }

    const bool finished = fin_f > 0.5f;
    const bool valid0 = iv0 > 0.5f;

    float otv = tvv, otd = tdv;
    float iff, ivout;
    if (finished) {
        // itv==0 everywhere: passthrough; iff=1; iv unchanged.
        iff = 1.0f;
        ivout = iv0;
    } else if (!valid0) {
        // iv==0: no pushes, no ops, meet stays 0, hs stays 0 -> ifu=0.
        iff = 0.0f;
        ivout = 0.0f;
    } else if (j < 0) {
        // No op met: iv stays 1; iff = (exactly one push).
        ivout = 1.0f;
        iff = (i0 >= 0 && i1 < 0) ? 1.0f : 0.0f;
    } else if (i1 >= 0) {
        // fg==1: apply the op. h0 = top (most recent push), h1 = second.
        float h0 = s_td[i0];   // broadcast read
        float h1 = s_td[i1];   // broadcast read
        int op = s_amax[j];    // broadcast read
        float res;
        switch (op) {
            case 2: res = h1 + h0; break;
            case 3: res = h1 - h0; break;
            case 4: res = h1 * h0; break;
            case 5: res = h1 / (h0 + 1e-7f); break;
            case 6: res = powf(fmaxf(h1, 1e-7f), h0); break;
            default: res = 0.0f; break;   // op index 1 -> zero
        }
        if (t == i0) otd = res;
        if (t == i1 || t == j) otv = 0.0f;
        ivout = 1.0f;
        iff = 0.0f;
    } else {
        // Op met but stack underflow: iv -> 0, nothing written.
        ivout = 0.0f;
        iff = 0.0f;
    }

    // Coalesced writeback straight from registers (no barrier needed).
    out_tv[rbase + t] = otv;
    out_td[rbase + t] = otd;
    if (t == 0) {
        out_iff[b] = iff;
        out_iv[b] = ivout;
    }
}

extern "C" void kernel_launch(void* const* d_in, const int* in_sizes, int n_in,
                              void* d_out, int out_size, void* d_ws, size_t ws_size,
                              hipStream_t stream) {
    const float* tv_in = (const float*)d_in[0];   // trans_valid (B,S)
    const float* td_in = (const float*)d_in[1];   // trans_dense (B,S)
    const float* op_in = (const float*)d_in[2];   // trans_op (B,S,7)
    const float* if_fin = (const float*)d_in[3];  // if_finished (B,)
    const float* if_val = (const float*)d_in[4];  // if_valid (B,)
    const int* start_pos = (const int*)d_in[5];   // scalar

    float* out = (float*)d_out;
    float* out_tv = out;                                    // B*S
    float* out_td = out + (size_t)BB * SS;                  // B*S
    float* out_op = out + (size_t)2 * BB * SS;              // B*S*7
    float* out_iff = out + (size_t)9 * BB * SS;             // B
    float* out_iv = out + (size_t)9 * BB * SS + BB;         // B

    arth_kernel<<<BB, SS, 0, stream>>>(tv_in, td_in, op_in, if_fin, if_val,
                                       start_pos, out_tv, out_td, out_op,
                                       out_iff, out_iv);
}

// Round 3
// 16.734 us; speedup vs baseline: 1.1138x; 1.0681x over previous
//
#include <hip/hip_runtime.h>

#define BB 4096
#define SS 256
#define NOPS 7

typedef float f32x4 __attribute__((ext_vector_type(4)));

__global__ __launch_bounds__(256) void arth_kernel(
    const float* __restrict__ tv_in,
    const float* __restrict__ td_in,
    const float* __restrict__ op_in,
    const float* __restrict__ if_fin,
    const float* __restrict__ if_val,
    const int* __restrict__ start_pos_p,
    float* __restrict__ out_tv,
    float* __restrict__ out_td,
    float* __restrict__ out_op,
    float* __restrict__ out_iff,
    float* __restrict__ out_iv)
{
    __shared__ float s_op[SS * NOPS];
    __shared__ float s_td[SS];
    __shared__ unsigned char s_amax[SS];
    __shared__ unsigned long long sm_op[4];
    __shared__ unsigned long long sm_num[4];

    const int b = blockIdx.x;
    const int t = threadIdx.x;
    const size_t rbase = (size_t)b * SS;
    const size_t obase = (size_t)b * (SS * NOPS);

    // Block-uniform scalars: s_load, overlapped with the vector loads below.
    const int start_pos = *start_pos_p;
    const float fin_f = if_fin[b];
    const float iv0 = if_val[b];

    const f32x4* in4 = (const f32x4*)(op_in + obase);
    f32x4* o4 = (f32x4*)(out_op + obase);
    f32x4* s4 = (f32x4*)s_op;

    // ---- Phase 1: issue ALL global loads back-to-back (MLP). ----
    // 448 float4 = 256 (all threads) + 192 (t<192). ~37 B/lane in flight.
    f32x4 v0 = in4[t];
    f32x4 v1;
    if (t < 192) v1 = in4[256 + t];
    const float tvv = tv_in[rbase + t];
    const float tdv = td_in[rbase + t];

    // ---- Phase 2: drain once, then stores + LDS staging. ----
    // op copy is pure streaming, never re-read from global -> nontemporal.
    __builtin_nontemporal_store(v0, &o4[t]);
    s4[t] = v0;
    if (t < 192) {
        __builtin_nontemporal_store(v1, &o4[256 + t]);
        s4[256 + t] = v1;
    }
    s_td[t] = tdv;
    __syncthreads();

    // Per-position argmax over 7 ops (first-max-lowest-index = jnp.argmax).
    int am = 0;
    float best = s_op[t * NOPS];
    #pragma unroll
    for (int k = 1; k < NOPS; ++k) {
        float v = s_op[t * NOPS + k];
        if (v > best) { best = v; am = k; }
    }
    s_amax[t] = (unsigned char)am;

    const bool validtok = (t >= start_pos) && (tvv > 0.5f);
    const bool is_num = validtok && (am == 0);
    const bool is_op = validtok && (am != 0);

    unsigned long long mo = __ballot(is_op);
    unsigned long long mn = __ballot(is_num);
    if ((t & 63) == 0) {
        sm_op[t >> 6] = mo;
        sm_num[t >> 6] = mn;
    }
    __syncthreads();

    // All threads scan the 8 mask words (wave-uniform, broadcast LDS reads).
    unsigned long long w_op0 = sm_op[0], w_op1 = sm_op[1], w_op2 = sm_op[2], w_op3 = sm_op[3];
    unsigned long long w_nm[4] = { sm_num[0], sm_num[1], sm_num[2], sm_num[3] };

    // First valid op token j (or -1).
    int j = -1;
    if (w_op0)      j = __builtin_ctzll(w_op0);
    else if (w_op1) j = 64 + __builtin_ctzll(w_op1);
    else if (w_op2) j = 128 + __builtin_ctzll(w_op2);
    else if (w_op3) j = 192 + __builtin_ctzll(w_op3);

    // Top-two push indices strictly below j (or below S if no op).
    int i0 = -1, i1 = -1;
    #pragma unroll
    for (int ww = 3; ww >= 0; --ww) {
        if (i1 >= 0) continue;
        unsigned long long m = w_nm[ww];
        if (j >= 0) {
            int jw = j - ww * 64;
            if (jw <= 0) m = 0ull;
            else if (jw < 64) m &= ((1ull << jw) - 1ull);
        }
        while (m && i1 < 0) {
            int bit = 63 - __builtin_clzll(m);
            if (i0 < 0) i0 = ww * 64 + bit;
            else        i1 = ww * 64 + bit;
            m &= ~(1ull << bit);
        }
    }

    const bool finished = fin_f > 0.5f;
    const bool valid0 = iv0 > 0.5f;

    float otv = tvv, otd = tdv;
    float iff, ivout;
    if (finished) {
        iff = 1.0f;
        ivout = iv0;
    } else if (!valid0) {
        iff = 0.0f;
        ivout = 0.0f;
    } else if (j < 0) {
        ivout = 1.0f;
        iff = (i0 >= 0 && i1 < 0) ? 1.0f : 0.0f;
    } else if (i1 >= 0) {
        float h0 = s_td[i0];   // broadcast read
        float h1 = s_td[i1];   // broadcast read
        int op = s_amax[j];    // broadcast read
        float res;
        switch (op) {
            case 2: res = h1 + h0; break;
            case 3: res = h1 - h0; break;
            case 4: res = h1 * h0; break;
            case 5: res = h1 / (h0 + 1e-7f); break;
            case 6: res = powf(fmaxf(h1, 1e-7f), h0); break;
            default: res = 0.0f; break;   // op index 1 -> zero
        }
        if (t == i0) otd = res;
        if (t == i1 || t == j) otv = 0.0f;
        ivout = 1.0f;
        iff = 0.0f;
    } else {
        ivout = 0.0f;
        iff = 0.0f;
    }

    // Streaming writeback straight from registers.
    __builtin_nontemporal_store(otv, &out_tv[rbase + t]);
    __builtin_nontemporal_store(otd, &out_td[rbase + t]);
    if (t == 0) {
        out_iff[b] = iff;
        out_iv[b] = ivout;
    }
}

extern "C" void kernel_launch(void* const* d_in, const int* in_sizes, int n_in,
                              void* d_out, int out_size, void* d_ws, size_t ws_size,
                              hipStream_t stream) {
    const float* tv_in = (const float*)d_in[0];   // trans_valid (B,S)
    const float* td_in = (const float*)d_in[1];   // trans_dense (B,S)
    const float* op_in = (const float*)d_in[2];   // trans_op (B,S,7)
    const float* if_fin = (const float*)d_in[3];  // if_finished (B,)
    const float* if_val = (const float*)d_in[4];  // if_valid (B,)
    const int* start_pos = (const int*)d_in[5];   // scalar

    float* out = (float*)d_out;
    float* out_tv = out;                                    // B*S
    float* out_td = out + (size_t)BB * SS;                  // B*S
    float* out_op = out + (size_t)2 * BB * SS;              // B*S*7
    float* out_iff = out + (size_t)9 * BB * SS;             // B
    float* out_iv = out + (size_t)9 * BB * SS + BB;         // B

    arth_kernel<<<BB, SS, 0, stream>>>(tv_in, td_in, op_in, if_fin, if_val,
                                       start_pos, out_tv, out_td, out_op,
                                       out_iff, out_iv);
}